// Round 5
// baseline (167.413 us; speedup 1.0000x reference)
//
#include <hip/hip_runtime.h>
#include <math.h>

#define N2C 16000
#define N1C 4000
#define N0C 1000
#define DEG 32
#define CH 256      // H*O
#define NHEAD 4
#define ODIM 64
#define ALPHA 0.2f
#define LDP 264     // padded LDS row pitch (ushorts): 264*2=528 B, 16B-aligned, 2-way banks
#define EPAD 36     // padded edge count (33 real + 3 zero-weight pads), 9 per row-group

typedef __attribute__((ext_vector_type(8))) short bf16x8;
typedef __attribute__((ext_vector_type(4))) float f32x4;

__device__ __forceinline__ ushort f2bf(float f) {
    unsigned u = __float_as_uint(f);
    unsigned r = (u + 0x7fffu + ((u >> 16) & 1u)) >> 16;   // RTNE
    return (ushort)r;
}
__device__ __forceinline__ float bf2f(ushort h) {
    return __uint_as_float(((unsigned)h) << 16);
}

// ---------------- repack weights -> bf16 hi/lo, transposed to [n][k] ----------------
__global__ __launch_bounds__(256) void repack_kernel(
    const float* __restrict__ W0, const float* __restrict__ W1,
    const float* __restrict__ linW,
    ushort* __restrict__ Wth, ushort* __restrict__ Wtl)
{
    int g = blockIdx.x * 256 + threadIdx.x;   // 0 .. 3*65536-1
    int mat = g >> 16;
    int idx = g & 65535;
    int c = idx >> 8, k = idx & 255;
    float v;
    if (mat == 0)      v = W0[(c >> 6) * (256 * 64) + k * 64 + (c & 63)];
    else if (mat == 1) v = W1[(c >> 6) * (256 * 64) + k * 64 + (c & 63)];
    else               v = linW[c * 256 + k];
    ushort h = f2bf(v);
    Wth[g] = h;
    Wtl[g] = f2bf(v - bf2f(h));
}

// ---------------- split-bf16 MFMA GEMM + fused score epilogue -----------------------
// out[M x 256] = A[M x 256] * B[256 x 256];  B as hi/lo bf16 transposed [n][k].
// AF32=1: A fp32 row-major, converted ONCE per block into LDS hi/lo (shared by 4 waves).
// SC=1: also emit s_t/s_n (per-head dots with avec) — wave w holds head w's 64 cols.
template<int RT, int EPI, int AF32, int SC>
__global__ __launch_bounds__(256) void gemm_mfma(
    const float* __restrict__ Af,
    const ushort* __restrict__ Ah, const ushort* __restrict__ Al,
    const ushort* __restrict__ Bh, const ushort* __restrict__ Bl,
    const float* __restrict__ bias, const float* __restrict__ avec,
    float* __restrict__ out, float* __restrict__ s_t, float* __restrict__ s_n, int M)
{
    __shared__ ushort sah[AF32 ? RT * 16 * LDP : 1];
    __shared__ ushort sal[AF32 ? RT * 16 * LDP : 1];

    const int wave = threadIdx.x >> 6;
    const int lane = threadIdx.x & 63;
    const int quad = lane >> 4, l16 = lane & 15;
    const int row0 = blockIdx.x * (RT * 16);
    const int col0 = wave * 64;

    if (AF32) {
        // cooperative stage: fp32 A tile -> hi/lo bf16 in LDS (once per block)
        for (int idx = threadIdx.x; idx < RT * 16 * 64; idx += 256) {
            int row = idx >> 6, c4 = idx & 63;
            int gr = row0 + row; if (gr >= M) gr = M - 1;
            float4 f = ((const float4*)Af)[gr * 64 + c4];
            ushort4 h, l;
            h.x = f2bf(f.x); l.x = f2bf(f.x - bf2f(h.x));
            h.y = f2bf(f.y); l.y = f2bf(f.y - bf2f(h.y));
            h.z = f2bf(f.z); l.z = f2bf(f.z - bf2f(h.z));
            h.w = f2bf(f.w); l.w = f2bf(f.w - bf2f(h.w));
            *(ushort4*)(&sah[row * LDP + c4 * 4]) = h;
            *(ushort4*)(&sal[row * LDP + c4 * 4]) = l;
        }
        __syncthreads();
    }

    f32x4 acc[RT][4];
#pragma unroll
    for (int r = 0; r < RT; ++r)
#pragma unroll
        for (int c = 0; c < 4; ++c) acc[r][c] = (f32x4){0.f, 0.f, 0.f, 0.f};

    int arow[RT];
#pragma unroll
    for (int r = 0; r < RT; ++r) {
        int rr = row0 + r * 16 + l16;
        arow[r] = (rr < M) ? rr : (M - 1);   // clamp: reads stay in-bounds
    }
    const int kbase = quad * 8;

    for (int k0 = 0; k0 < 256; k0 += 32) {
        bf16x8 a_h[RT], a_l[RT], b_h[4], b_l[4];
#pragma unroll
        for (int r = 0; r < RT; ++r) {
            if (AF32) {
                int loff = (r * 16 + l16) * LDP + k0 + kbase;
                a_h[r] = *(const bf16x8*)(&sah[loff]);   // ds_read_b128, 2-way banks
                a_l[r] = *(const bf16x8*)(&sal[loff]);
            } else {
                int off = arow[r] * 256 + k0 + kbase;
                a_h[r] = *(const bf16x8*)(Ah + off);
                a_l[r] = *(const bf16x8*)(Al + off);
            }
        }
#pragma unroll
        for (int c = 0; c < 4; ++c) {
            int off = (col0 + c * 16 + l16) * 256 + k0 + kbase;
            b_h[c] = *(const bf16x8*)(Bh + off);
            b_l[c] = *(const bf16x8*)(Bl + off);
        }
#pragma unroll
        for (int r = 0; r < RT; ++r)
#pragma unroll
            for (int c = 0; c < 4; ++c) {
                acc[r][c] = __builtin_amdgcn_mfma_f32_16x16x32_bf16(a_h[r], b_h[c], acc[r][c], 0, 0, 0);
                acc[r][c] = __builtin_amdgcn_mfma_f32_16x16x32_bf16(a_h[r], b_l[c], acc[r][c], 0, 0, 0);
                acc[r][c] = __builtin_amdgcn_mfma_f32_16x16x32_bf16(a_l[r], b_h[c], acc[r][c], 0, 0, 0);
            }
    }

    // C/D layout: col = lane&15, row = quad*4 + reg  [measured m89/m91]
#pragma unroll
    for (int r = 0; r < RT; ++r)
#pragma unroll
        for (int c = 0; c < 4; ++c) {
            int col = col0 + c * 16 + l16;
#pragma unroll
            for (int reg = 0; reg < 4; ++reg) {
                int row = row0 + r * 16 + quad * 4 + reg;
                if (row < M) {
                    float v = acc[r][c][reg];
                    if (EPI == 1) v = tanhf(v + bias[col]);
                    out[row * 256 + col] = v;
                }
            }
        }

    if (SC) {
        // head hd == wave; per-lane channels: c*16+l16, c=0..3
        float at[4], an[4];
#pragma unroll
        for (int c = 0; c < 4; ++c) {
            at[c] = avec[wave * 128 + c * 16 + l16];
            an[c] = avec[wave * 128 + 64 + c * 16 + l16];
        }
#pragma unroll
        for (int r = 0; r < RT; ++r) {
            float pt[4] = {0.f, 0.f, 0.f, 0.f}, pn[4] = {0.f, 0.f, 0.f, 0.f};
#pragma unroll
            for (int c = 0; c < 4; ++c)
#pragma unroll
                for (int reg = 0; reg < 4; ++reg) {
                    pt[reg] += acc[r][c][reg] * at[c];
                    pn[reg] += acc[r][c][reg] * an[c];
                }
#pragma unroll
            for (int reg = 0; reg < 4; ++reg)
#pragma unroll
                for (int m = 1; m < 16; m <<= 1) {
                    pt[reg] += __shfl_xor(pt[reg], m);
                    pn[reg] += __shfl_xor(pn[reg], m);
                }
            if (l16 == 0) {
#pragma unroll
                for (int reg = 0; reg < 4; ++reg) {
                    int row = row0 + r * 16 + quad * 4 + reg;
                    if (row < M) {
                        s_t[wave * M + row] = pt[reg];
                        s_n[wave * M + row] = pn[reg];
                    }
                }
            }
        }
    }
}

// ---------------- per-target: wave-parallel dedupe+softmax, batched float4 gather ---
__global__ __launch_bounds__(256) void att_kernel(
    const float* __restrict__ hprev, const int* __restrict__ nbr_arr,
    const float* __restrict__ s_t, const float* __restrict__ s_n,
    ushort* __restrict__ outhi, ushort* __restrict__ outlo, int T, int Nsrc)
{
    __shared__ int nbr[EPAD];
    __shared__ float att_s[NHEAD][EPAD];
    __shared__ float4 red[4][64];
    const int tgt = blockIdx.x;
    const int t = threadIdx.x;
    const int lane = t & 63;
    if (t < DEG) nbr[t] = nbr_arr[tgt * DEG + t];
    else if (t == DEG) nbr[DEG] = nbr_arr[T * DEG + tgt];  // self-loop edge
    else if (t < EPAD) nbr[t] = 0;                          // pad: valid row, weight 0
    __syncthreads();

    {   // wave = head; lane = edge index (33 edges), lanes 33..63 inert
        const int hd = t >> 6;
        int me = (lane <= DEG) ? nbr[lane] : 0;
        int k = (lane <= DEG) ? 1 : 0;
#pragma unroll
        for (int j = 0; j < DEG; ++j) {          // dedupe scan via shuffle
            int v = __shfl(me, j);
            if (j < lane && v == me && lane <= DEG) k = 0;
        }
        float e = s_t[hd * Nsrc + tgt] + s_n[hd * Nsrc + me];
        e = (e >= 0.f) ? e : ALPHA * e;          // LeakyReLU(0.2)
        float em = k ? e : -1e30f;
        float m = em;
#pragma unroll
        for (int off = 1; off < 64; off <<= 1) m = fmaxf(m, __shfl_xor(m, off));
        float w = k ? __expf(e - m) : 0.f;
        float Z = w;
#pragma unroll
        for (int off = 1; off < 64; off <<= 1) Z += __shfl_xor(Z, off);
        if (lane < EPAD) att_s[hd][lane] = (lane <= DEG) ? (w / Z) : 0.f;
    }
    __syncthreads();

    // aggregation: thread = (rg = t>>6 row-group, cq = t&63 channel-quad)
    // rg handles edges rg*9 .. rg*9+8 — all unconditional (pads have w=0, row 0)
    const int cq = t & 63;
    const int rg = t >> 6;
    const int hd = cq >> 4;
    const float4* hp4 = (const float4*)hprev;
    float w[9];
    int rrow[9];
#pragma unroll
    for (int ii = 0; ii < 9; ++ii) {
        w[ii] = att_s[hd][rg * 9 + ii];
        rrow[ii] = nbr[rg * 9 + ii];
    }
    float4 acc = make_float4(0.f, 0.f, 0.f, 0.f);
#pragma unroll
    for (int ii = 0; ii < 9; ++ii) {
        float4 v = hp4[(size_t)rrow[ii] * 64 + cq];   // 9 loads, no guards -> batched
        acc.x += w[ii] * v.x; acc.y += w[ii] * v.y;
        acc.z += w[ii] * v.z; acc.w += w[ii] * v.w;
    }
    red[rg][cq] = acc;
    __syncthreads();
    if (t < 64) {
        float4 s0 = red[0][t], s1 = red[1][t], s2 = red[2][t], s3 = red[3][t];
        float4 s;
        s.x = s0.x + s1.x + s2.x + s3.x;
        s.y = s0.y + s1.y + s2.y + s3.y;
        s.z = s0.z + s1.z + s2.z + s3.z;
        s.w = s0.w + s1.w + s2.w + s3.w;
        s.x = (s.x > 0.f) ? s.x : expm1f(s.x);   // ELU
        s.y = (s.y > 0.f) ? s.y : expm1f(s.y);
        s.z = (s.z > 0.f) ? s.z : expm1f(s.z);
        s.w = (s.w > 0.f) ? s.w : expm1f(s.w);
        ushort4 h, l;
        h.x = f2bf(s.x); l.x = f2bf(s.x - bf2f(h.x));
        h.y = f2bf(s.y); l.y = f2bf(s.y - bf2f(h.y));
        h.z = f2bf(s.z); l.z = f2bf(s.z - bf2f(h.z));
        h.w = f2bf(s.w); l.w = f2bf(s.w - bf2f(h.w));
        ((ushort4*)outhi)[tgt * 64 + t] = h;
        ((ushort4*)outlo)[tgt * 64 + t] = l;
    }
}

extern "C" void kernel_launch(void* const* d_in, const int* in_sizes, int n_in,
                              void* d_out, int out_size, void* d_ws, size_t ws_size,
                              hipStream_t stream)
{
    const float* x    = (const float*)d_in[0];
    const float* W0   = (const float*)d_in[1];
    const float* a0   = (const float*)d_in[2];
    const float* W1   = (const float*)d_in[3];
    const float* a1   = (const float*)d_in[4];
    const float* linW = (const float*)d_in[5];
    const float* linb = (const float*)d_in[6];
    const int* adj1_nbr = (const int*)d_in[8];
    const int* adj0_nbr = (const int*)d_in[10];

    char* base = (char*)d_ws;
    ushort* Wth = (ushort*)base;                       // 3*65536 ushort = 384 KB
    ushort* Wtl = Wth + 3 * 65536;                     // 384 KB
    float*  st  = (float*)(base + 786432);             // 4*16000 f32
    float*  sn  = st + 65536;
    float*  h0  = (float*)(base + 1310720);            // 16000*256 f32 (reused as h1)
    ushort* xhi = (ushort*)(base + 1310720 + 16384000);// att outputs (bf16 hi/lo)
    ushort* xlo = xhi + 4096000;

    repack_kernel<<<768, 256, 0, stream>>>(W0, W1, linW, Wth, Wtl);

    // layer 1: h0 = x @ Wc0 (fp32 A staged+converted once per block in LDS) + scores
    gemm_mfma<2, 0, 1, 1><<<N2C / 32, 256, 0, stream>>>(
        x, nullptr, nullptr, Wth, Wtl, nullptr, a0, h0, st, sn, N2C);
    att_kernel<<<N1C, 256, 0, stream>>>(h0, adj1_nbr, st, sn, xhi, xlo, N1C, N2C);

    // layer 2: h1 = x1 @ Wc1 (h1 aliases h0) + fused scores
    gemm_mfma<1, 0, 0, 1><<<N1C / 16, 256, 0, stream>>>(
        nullptr, xhi, xlo, Wth + 65536, Wtl + 65536, nullptr, a1, h0, st, sn, N1C);
    att_kernel<<<N0C, 256, 0, stream>>>(h0, adj0_nbr, st, sn, xhi, xlo, N0C, N1C);

    // final Linear + Tanh
    gemm_mfma<1, 1, 0, 0><<<(N0C + 15) / 16, 256, 0, stream>>>(
        nullptr, xhi, xlo, Wth + 131072, Wtl + 131072, linb, nullptr,
        (float*)d_out, nullptr, nullptr, N0C);
}